// Round 6
// baseline (318.987 us; speedup 1.0000x reference)
//
#include <hip/hip_runtime.h>
#include <hip/hip_bf16.h>
#include <math.h>

// B=2, S=2048, H=2048, NH=16, HD=128
#define SEQ 2048
#define HID 2048
#define NHEAD 16
#define HDIM 128
#define LDK 4096   // fused QK row stride

typedef __bf16 bf16_t;
typedef __bf16 bf16x2 __attribute__((ext_vector_type(2)));
typedef __bf16 bf16x4_t __attribute__((ext_vector_type(4)));
typedef __bf16 bf16x8 __attribute__((ext_vector_type(8)));
typedef float f32x4 __attribute__((ext_vector_type(4)));
typedef float f32x16 __attribute__((ext_vector_type(16)));
typedef unsigned u32x4 __attribute__((ext_vector_type(4)));

#define MFMA16(a, b, c) __builtin_amdgcn_mfma_f32_16x16x32_bf16(a, b, c, 0, 0, 0)
#define MFMA32(a, b, c) __builtin_amdgcn_mfma_f32_32x32x16_bf16(a, b, c, 0, 0, 0)
#define GLOAD_LDS(g, l) \
  __builtin_amdgcn_global_load_lds((const __attribute__((address_space(1))) void*)(g), \
                                   (__attribute__((address_space(3))) void*)(l), 16, 0, 0)

static __device__ inline unsigned pk2(float lo, float hi) {
  bf16x2 t; t[0] = (bf16_t)lo; t[1] = (bf16_t)hi;
  return __builtin_bit_cast(unsigned, t);
}

// ---------------- cast kernels ----------------
__global__ void cast_hidden(const float* __restrict__ in, bf16_t* __restrict__ out) {
  int i = blockIdx.x * 256 + threadIdx.x;
  float4 v = ((const float4*)in)[i];
  bf16x4_t b;
  b[0] = (bf16_t)v.x; b[1] = (bf16_t)v.y; b[2] = (bf16_t)v.z; b[3] = (bf16_t)v.w;
  ((bf16x4_t*)out)[i] = b;
}

__global__ void cast_weights(const float* __restrict__ a, const float* __restrict__ b,
                             const float* __restrict__ c, const float* __restrict__ d,
                             bf16_t* __restrict__ out) {
  const float* srcs[4] = {a, b, c, d};
  const float* src = srcs[blockIdx.y];
  bf16_t* dst = out + (size_t)blockIdx.y * (HID * HID);
  int i = blockIdx.x * 256 + threadIdx.x;
  float4 v = ((const float4*)src)[i];
  bf16x4_t o;
  o[0] = (bf16_t)v.x; o[1] = (bf16_t)v.y; o[2] = (bf16_t)v.z; o[3] = (bf16_t)v.w;
  ((bf16x4_t*)dst)[i] = o;
}

// ---------------- 256x256 8-phase GEMM (grid MUST be 256 = 16x16 tiles) ----------
// BM=BN=256, BK=64, 8 waves (2Mx4N), 512 thr, LDS 128KB. Conflict-free swizzle
// chunk = lg ^ ((row>>1)&3). XCD 8x4 super-tile (exactly one grid-wave, no tail).
__global__ __launch_bounds__(512, 2) void gemm256(
    const bf16_t* __restrict__ A, const bf16_t* __restrict__ Bw,
    bf16_t* __restrict__ Cb, float* __restrict__ Cf, int M, int N, int K) {
  __shared__ char smem[131072];
  const int tid = threadIdx.x, lane = tid & 63, wid = tid >> 6;
  const int wr = wid >> 2, wc = wid & 3;          // 2 x 4 wave grid
  const int lr = lane & 15, lg = lane >> 4;
  // grid 256 = 16x16 tiles; XCD owns an 8-row x 4-col super-tile
  const int xcd = blockIdx.x & 7, l = blockIdx.x >> 3;   // l in 0..31
  const int brow = (xcd >> 2) * 8 + (l >> 2);
  const int bcol = (xcd & 3) * 4 + (l & 3);
  const int NT = K >> 6;                           // K-tiles of 64

  const bf16_t* Ab = A + (size_t)(brow * 256) * K;
  const bf16_t* Bb = Bw + (size_t)(bcol * 256) * K;

  f32x4 acc[8][4] = {};
  bf16x8 af[4], bfr[4];
  const int swz = (lg ^ ((lr >> 1) & 3)) << 4;     // conflict-free chunk select

#define STAGE_HALF(t_, op, kh)                                                        \
  {                                                                                   \
    int tt = (t_) < NT ? (t_) : NT - 1;                                               \
    const bf16_t* gsrc = (op) ? Bb : Ab;                                              \
    char* ldst = smem + (tt & 1) * 65536 + (op) * 32768 + (kh) * 16384;               \
    _Pragma("unroll") for (int is = 0; is < 2; ++is) {                                \
      int p = tid + is * 512;                                                         \
      int row = p >> 2, ch = p & 3;                                                   \
      GLOAD_LDS(gsrc + (size_t)row * K + tt * 64 + (kh) * 32 +                        \
                    ((ch ^ ((row >> 1) & 3)) * 8),                                    \
                ldst + p * 16);                                                       \
    }                                                                                 \
  }

#define PHASE(cb, kh, mh, LOADB, STAGECALL, VM)                                       \
  {                                                                                   \
    _Pragma("unroll") for (int mf = 0; mf < 4; ++mf) {                                \
      int row = wr * 128 + (mh) * 64 + mf * 16 + lr;                                  \
      af[mf] = *(const bf16x8*)(smem + (cb) * 65536 + (kh) * 16384 + row * 64 + swz); \
    }                                                                                 \
    if (LOADB) {                                                                      \
      _Pragma("unroll") for (int nf = 0; nf < 4; ++nf) {                              \
        int row = wc * 64 + nf * 16 + lr;                                             \
        bfr[nf] = *(const bf16x8*)(smem + (cb) * 65536 + 32768 + (kh) * 16384 +       \
                                   row * 64 + swz);                                   \
      }                                                                               \
    }                                                                                 \
    STAGECALL;                                                                        \
    __builtin_amdgcn_s_barrier();                                                     \
    asm volatile("s_waitcnt lgkmcnt(0)" ::: "memory");                                \
    __builtin_amdgcn_sched_barrier(0);                                                \
    __builtin_amdgcn_s_setprio(1);                                                    \
    _Pragma("unroll") for (int mf = 0; mf < 4; ++mf)                                  \
      _Pragma("unroll") for (int nf = 0; nf < 4; ++nf)                                \
        acc[(mh) * 4 + mf][nf] = MFMA16(af[mf], bfr[nf], acc[(mh) * 4 + mf][nf]);     \
    __builtin_amdgcn_s_setprio(0);                                                    \
    if (VM) { asm volatile("s_waitcnt vmcnt(6)" ::: "memory"); }                      \
    __builtin_amdgcn_s_barrier();                                                     \
    __builtin_amdgcn_sched_barrier(0);                                                \
  }

  // Prologue: stage t0.{Bk0,Ak0,Bk1,Ak1} + t1.{Bk0,Ak0,Bk1}
  STAGE_HALF(0, 1, 0); STAGE_HALF(0, 0, 0); STAGE_HALF(0, 1, 1); STAGE_HALF(0, 0, 1);
  STAGE_HALF(1, 1, 0); STAGE_HALF(1, 0, 0); STAGE_HALF(1, 1, 1);
  asm volatile("s_waitcnt vmcnt(6)" ::: "memory");   // t0 complete; t1 in flight
  __builtin_amdgcn_s_barrier();
  __builtin_amdgcn_sched_barrier(0);

  const int NI = NT >> 1;     // 2 K-tiles per iteration
  for (int i = 0; i < NI; ++i) {
    const int t2 = 2 * i;
    PHASE(0, 0, 0, 1, STAGE_HALF(t2 + 1, 0, 1), 0);   // p1
    PHASE(0, 0, 1, 0, STAGE_HALF(t2 + 2, 1, 0), 0);   // p2
    PHASE(0, 1, 0, 1, STAGE_HALF(t2 + 2, 0, 0), 0);   // p3
    PHASE(0, 1, 1, 0, STAGE_HALF(t2 + 2, 1, 1), 1);   // p4 (vmcnt 6)
    PHASE(1, 0, 0, 1, STAGE_HALF(t2 + 2, 0, 1), 0);   // p5
    PHASE(1, 0, 1, 0, STAGE_HALF(t2 + 3, 1, 0), 0);   // p6
    PHASE(1, 1, 0, 1, STAGE_HALF(t2 + 3, 0, 0), 0);   // p7
    PHASE(1, 1, 1, 0, STAGE_HALF(t2 + 3, 1, 1), 1);   // p8 (vmcnt 6)
  }
#undef PHASE
#undef STAGE_HALF

#pragma unroll
  for (int mi = 0; mi < 8; ++mi)
#pragma unroll
    for (int nf = 0; nf < 4; ++nf)
#pragma unroll
      for (int r = 0; r < 4; ++r) {
        int row = brow * 256 + wr * 128 + (mi >> 2) * 64 + (mi & 3) * 16 + lg * 4 + r;
        int col = bcol * 256 + wc * 64 + nf * 16 + lr;
        float v = acc[mi][nf][r];
        if (Cf) Cf[(size_t)row * N + col] = v;
        else    Cb[(size_t)row * N + col] = (bf16_t)v;
      }
}

// ---------------- GEMM: C = A * B^T, 2-phase double-buffered (128x128) -------------
__global__ __launch_bounds__(256, 3) void gemm_bt(
    const bf16_t* __restrict__ A, const bf16_t* __restrict__ Bw,
    bf16_t* __restrict__ Cb, float* __restrict__ Cf,
    int M, int N, int K) {
  __shared__ bf16_t As[2][128 * 32];
  __shared__ bf16_t Bs[2][128 * 32];
  const int tid = threadIdx.x;
  const int lane = tid & 63, wid = tid >> 6;
  const int wr = wid >> 1, wc = wid & 1;
  const int lr = lane & 15, lg = lane >> 4;
  const int nwg = gridDim.x;
  const int lid = (blockIdx.x & 7) * (nwg >> 3) + (blockIdx.x >> 3);
  const int nbc = N >> 7;
  const int brow = lid / nbc, bcol = lid % nbc;

  f32x4 acc[4][4] = {};
  const int swz = lg ^ ((lr >> 1) & 3);

  const int srow = tid >> 2, sch = tid & 3;
#define GSTAGE(k0, bb)                                                                   \
  {                                                                                      \
    _Pragma("unroll") for (int is = 0; is < 2; ++is) {                                   \
      int row = srow + is * 64;                                                          \
      int g = (sch ^ ((row >> 1) & 3)) * 8;                                              \
      GLOAD_LDS(A + (size_t)(brow * 128 + row) * K + (k0) + g,                           \
                &As[bb][(row * 4 + sch) * 8]);                                           \
      GLOAD_LDS(Bw + (size_t)(bcol * 128 + row) * K + (k0) + g,                          \
                &Bs[bb][(row * 4 + sch) * 8]);                                           \
    }                                                                                    \
  }

  GSTAGE(0, 0);
  __syncthreads();

  const int nt = K / 32;
  for (int t = 0; t < nt; ++t) {
    const int cb = t & 1;
    if (t + 1 < nt) GSTAGE((t + 1) * 32, cb ^ 1);
    bf16x8 af[4], bfr[4];
#pragma unroll
    for (int m = 0; m < 4; ++m)
      af[m] = *(const bf16x8*)(&As[cb][(wr * 64 + m * 16 + lr) * 32 + swz * 8]);
#pragma unroll
    for (int n = 0; n < 4; ++n)
      bfr[n] = *(const bf16x8*)(&Bs[cb][(wc * 64 + n * 16 + lr) * 32 + swz * 8]);
#pragma unroll
    for (int m = 0; m < 4; ++m)
#pragma unroll
      for (int n = 0; n < 4; ++n)
        acc[m][n] = MFMA16(af[m], bfr[n], acc[m][n]);
    __syncthreads();
  }
#undef GSTAGE

#pragma unroll
  for (int m = 0; m < 4; ++m)
#pragma unroll
    for (int n = 0; n < 4; ++n)
#pragma unroll
      for (int r = 0; r < 4; ++r) {
        int row = brow * 128 + wr * 64 + m * 16 + lg * 4 + r;
        int col = bcol * 128 + wc * 64 + n * 16 + lr;
        float v = acc[m][n][r];
        if (Cf) Cf[(size_t)row * N + col] = v;
        else    Cb[(size_t)row * N + col] = (bf16_t)v;
      }
}

// ---------------- RoPE in-place on QK buffer (stride LDK); Q pre-scaled ----------
__global__ void rope_qk(bf16_t* __restrict__ QK,
                        const float* __restrict__ cost, const float* __restrict__ sint) {
  const float SCALE = 0.08838834764831845f;  // 1/sqrt(128)
  int idx = blockIdx.x * 256 + threadIdx.x;            // total = 4096*16*8 = 524288
  int d8 = idx & 7;
  int t = idx >> 3;
  int h = t & 15;
  int row = t >> 4;
  int s = row & (SEQ - 1);
  size_t base = (size_t)row * LDK + h * HDIM;
  const float4* cp = (const float4*)(cost + s * HDIM);
  const float4* sp = (const float4*)(sint + s * HDIM);
  float4 c0a = cp[d8 * 2], c0b = cp[d8 * 2 + 1];
  float4 c1a = cp[16 + d8 * 2], c1b = cp[16 + d8 * 2 + 1];
  float4 s0a = sp[d8 * 2], s0b = sp[d8 * 2 + 1];
  float4 s1a = sp[16 + d8 * 2], s1b = sp[16 + d8 * 2 + 1];
  float c0[8] = {c0a.x, c0a.y, c0a.z, c0a.w, c0b.x, c0b.y, c0b.z, c0b.w};
  float c1[8] = {c1a.x, c1a.y, c1a.z, c1a.w, c1b.x, c1b.y, c1b.z, c1b.w};
  float s0[8] = {s0a.x, s0a.y, s0a.z, s0a.w, s0b.x, s0b.y, s0b.z, s0b.w};
  float s1[8] = {s1a.x, s1a.y, s1a.z, s1a.w, s1b.x, s1b.y, s1b.z, s1b.w};

  bf16_t* Q = QK;
  bf16_t* K = QK + 2048;
  bf16x8 qlo = *(bf16x8*)(Q + base + d8 * 8);
  bf16x8 qhi = *(bf16x8*)(Q + base + 64 + d8 * 8);
  bf16x8 klo = *(bf16x8*)(K + base + d8 * 8);
  bf16x8 khi = *(bf16x8*)(K + base + 64 + d8 * 8);
  bf16x8 qlo2, qhi2, klo2, khi2;
#pragma unroll
  for (int j = 0; j < 8; ++j) {
    float q0 = (float)qlo[j], q1 = (float)qhi[j];
    qlo2[j] = (bf16_t)((q0 * c0[j] - q1 * s0[j]) * SCALE);
    qhi2[j] = (bf16_t)((q1 * c1[j] + q0 * s1[j]) * SCALE);
    float k0 = (float)klo[j], k1 = (float)khi[j];
    klo2[j] = (bf16_t)(k0 * c0[j] - k1 * s0[j]);
    khi2[j] = (bf16_t)(k1 * c1[j] + k0 * s1[j]);
  }
  *(bf16x8*)(Q + base + d8 * 8) = qlo2;
  *(bf16x8*)(Q + base + 64 + d8 * 8) = qhi2;
  *(bf16x8*)(K + base + d8 * 8) = klo2;
  *(bf16x8*)(K + base + 64 + d8 * 8) = khi2;
}

// ---------------- V transpose: Vf (B*S x H) -> Vt[b][h][d][s] ----------------
__global__ void transpose_v(const bf16_t* __restrict__ Vf, bf16_t* __restrict__ Vt) {
  __shared__ bf16_t t[32][33];
  int tx = threadIdx.x & 31, ty = threadIdx.x >> 5;
  int r0 = blockIdx.y * 32, c0 = blockIdx.x * 32;
#pragma unroll
  for (int j = 0; j < 4; ++j)
    t[ty + j * 8][tx] = Vf[(size_t)(r0 + ty + j * 8) * HID + c0 + tx];
  __syncthreads();
#pragma unroll
  for (int j = 0; j < 4; ++j) {
    int c = c0 + ty + j * 8;
    int r = r0 + tx;
    int h = c >> 7, d = c & 127, b = r >> 11, s = r & (SEQ - 1);
    Vt[(((size_t)(b * NHEAD + h)) * HDIM + d) * SEQ + s] = t[tx][ty + j * 8];
  }
}

// ---------------- mask transpose: mask[b][0][q][k] f32 -> maskT[b][k][q] bf16 -------
__global__ void mask_t(const float* __restrict__ m, bf16_t* __restrict__ mt) {
  __shared__ float t[32][33];
  int tx = threadIdx.x & 31, ty = threadIdx.x >> 5;
  int r0 = blockIdx.y * 32, c0 = blockIdx.x * 32;
  const float* mb = m + (size_t)blockIdx.z * SEQ * SEQ;
  bf16_t* mtb = mt + (size_t)blockIdx.z * SEQ * SEQ;
#pragma unroll
  for (int j = 0; j < 4; ++j)
    t[ty + j * 8][tx] = mb[(size_t)(r0 + ty + j * 8) * SEQ + c0 + tx];
  __syncthreads();
#pragma unroll
  for (int j = 0; j < 4; ++j)
    mtb[(size_t)(c0 + ty + j * 8) * SEQ + r0 + tx] = (bf16_t)t[tx][ty + j * 8];
}

// ---------------- flash attention fwd: swapped-QK 32x32, in-register softmax ----------
// maskT[b][key][q] bf16 -> coalesced per-lane mask loads (lane q = consecutive).
__global__ __launch_bounds__(512, 2) void flash_fwd(
    const bf16_t* __restrict__ Qf, const bf16_t* __restrict__ Kf,
    const bf16_t* __restrict__ Vt, const bf16_t* __restrict__ maskT,
    bf16_t* __restrict__ AO) {
  __shared__ char smem[131072];          // K 2x32K | V 2x32K
  char* KsB = smem;
  char* VsB = smem + 65536;
  const int tid = threadIdx.x, lane = tid & 63, wid = tid >> 6;
  const int q32 = lane & 31, hi = lane >> 5;

  const int x = blockIdx.x;
  const int bh = x & 31, qt = x >> 5;
  const int b = bh >> 4, h = bh & 15;
  const int qg = qt * 256 + wid * 32 + q32;

  // Q fragments (B-operand): lane holds Q[q=lane&31][d = ds*16 + hi*8 + j]
  bf16x8 qf[8];
  const bf16_t* qptr = Qf + (size_t)(b * SEQ + qg) * LDK + h * HDIM + hi * 8;
#pragma unroll
  for (int ds = 0; ds < 8; ++ds) qf[ds] = *(const bf16x8*)(qptr + ds * 16);

  // lane's mask column: maskT[b][key][qg]  (32 consecutive lanes = 64B)
  const bf16_t* mQ = maskT + (size_t)b * SEQ * SEQ + qg;

  float mrun = -INFINITY, lpart = 0.f;
  f32x16 o[4] = {};

#define STAGE_KV(kt_, bb)                                                                \
  {                                                                                      \
    const int kb0_ = (kt_) * 128;                                                        \
    _Pragma("unroll") for (int is = 0; is < 4; ++is) {                                   \
      int p = tid + is * 512;                                                            \
      int row = p >> 4, ch = p & 15;                                                     \
      int src = (ch * 16) ^ ((row & 7) << 4);                                            \
      GLOAD_LDS((const char*)(Kf + (size_t)(b * SEQ + kb0_ + row) * LDK + h * HDIM) +    \
                    src,                                                                 \
                KsB + (bb) * 32768 + p * 16);                                            \
      GLOAD_LDS((const char*)(Vt + (size_t)(bh * HDIM + row) * SEQ + kb0_) + src,        \
                VsB + (bb) * 32768 + p * 16);                                            \
    }                                                                                    \
  }

  STAGE_KV(0, 0);
  __syncthreads();

  const int NT = SEQ / 128;
  for (int kt = 0; kt < NT; ++kt) {
    const int cur = kt & 1;
    const int kb0 = kt * 128;
    if (kt + 1 < NT) STAGE_KV(kt + 1, cur ^ 1);

#pragma unroll
    for (int kb = 0; kb < 4; ++kb) {
      // init accumulator with mask (C[key][q]: key = (reg&3)+8*(reg>>2)+4*hi)
      f32x16 sacc;
#pragma unroll
      for (int r = 0; r < 16; ++r) {
        int key = kb0 + kb * 32 + (r & 3) + 8 * (r >> 2) + 4 * hi;
        sacc[r] = (float)mQ[(size_t)key * SEQ];
      }
      // QK^T over d=128: A = K frag from LDS (row=key, k=d)
#pragma unroll
      for (int ds = 0; ds < 8; ++ds) {
        int row = kb * 32 + q32;
        bf16x8 kfr = *(const bf16x8*)(KsB + cur * 32768 + row * 256 +
                                      ((ds * 32 + hi * 16) ^ ((row & 7) << 4)));
        sacc = MFMA32(kfr, qf[ds], sacc);
      }

      // row max over this 32-key group (lane pair shares q)
      float mx = sacc[0];
#pragma unroll
      for (int r = 1; r < 16; ++r) mx = fmaxf(mx, sacc[r]);
      mx = fmaxf(mx, __shfl_xor(mx, 32, 64));
      // defer-max (T13)
      if (!__all(mx <= mrun + 8.f)) {
        float mnew = fmaxf(mrun, mx);
        float corr = __expf(mrun - mnew);
        mrun = mnew;
        lpart *= corr;
#pragma unroll
        for (int d0 = 0; d0 < 4; ++d0)
#pragma unroll
          for (int r = 0; r < 16; ++r) o[d0][r] *= corr;
      }

      // P = exp(s - m); per-lane partial row sum
      float p[16];
      float rs = 0.f;
#pragma unroll
      for (int r = 0; r < 16; ++r) {
        p[r] = __expf(sacc[r] - mrun);
        rs += p[r];
      }
      lpart += rs;

      // re-layout P to PV B-fragments and run PV for this 32-key group
#pragma unroll
      for (int s = 0; s < 2; ++s) {
        unsigned A1 = pk2(p[8 * s + 0], p[8 * s + 1]);
        unsigned A2 = pk2(p[8 * s + 2], p[8 * s + 3]);
        unsigned B1 = pk2(p[8 * s + 4], p[8 * s + 5]);
        unsigned B2 = pk2(p[8 * s + 6], p[8 * s + 7]);
        unsigned A1s = __shfl_xor(A1, 32, 64);
        unsigned A2s = __shfl_xor(A2, 32, 64);
        unsigned B1s = __shfl_xor(B1, 32, 64);
        unsigned B2s = __shfl_xor(B2, 32, 64);
        unsigned w0 = hi ? B1s : A1;
        unsigned w1 = hi ? B2s : A2;
        unsigned w2 = hi ? B1 : A1s;
        unsigned w3 = hi ? B2 : A2s;
        u32x4 W = {w0, w1, w2, w3};
        bf16x8 pav = __builtin_bit_cast(bf16x8, W);
        const int gs = kb * 2 + s;
#pragma unroll
        for (int d0 = 0; d0 < 4; ++d0) {
          int vrow = d0 * 32 + q32;
          bf16x8 vf = *(const bf16x8*)(VsB + cur * 32768 + vrow * 256 +
                                       ((gs * 32 + hi * 16) ^ ((vrow & 7) << 4)));
          o[d0] = MFMA32(vf, pav, o[d0]);
        }
      }
    }
    __syncthreads();
  }
#undef STAGE_KV

  // epilogue: full row sum, normalize, write AO (pack bf16 pairs)
  float l = lpart + __shfl_xor(lpart, 32, 64);
  float rl = 1.f / l;
  bf16_t* aorow = AO + (size_t)(b * SEQ + qg) * HID + h * HDIM;
#pragma unroll
  for (int d0 = 0; d0 < 4; ++d0)
#pragma unroll
    for (int g = 0; g < 4; ++g) {
      unsigned lo = pk2(o[d0][4 * g + 0] * rl, o[d0][4 * g + 1] * rl);
      unsigned hi2 = pk2(o[d0][4 * g + 2] * rl, o[d0][4 * g + 3] * rl);
      int d = d0 * 32 + 8 * g + 4 * hi;
      *(unsigned*)(aorow + d) = lo;
      *(unsigned*)(aorow + d + 2) = hi2;
    }
}

// ---------------- launch ----------------
extern "C" void kernel_launch(void* const* d_in, const int* in_sizes, int n_in,
                              void* d_out, int out_size, void* d_ws, size_t ws_size,
                              hipStream_t stream) {
  const float* hidden = (const float*)d_in[0];
  const float* cost   = (const float*)d_in[1];
  const float* sint   = (const float*)d_in[2];
  const float* mask   = (const float*)d_in[3];
  const float* Wq     = (const float*)d_in[4];
  const float* Wk     = (const float*)d_in[5];
  const float* Wv     = (const float*)d_in[6];
  const float* Wo     = (const float*)d_in[7];
  float* out = (float*)d_out;
  char* ws = (char*)d_ws;

  // layout (bytes), peak 100.66 MB:
  //   Af    @ 0          16.78 MB  (dead after V gemm)   -> Vt aliases after
  //   Wqb   @ 16777216   [Wq;Wk;Wv;Wo] 4x8.39 MB (Wob @ 41943040 live to end)
  //   QK    @ 50331648   33.55 MB  (4096 x 4096 bf16)
  //   Vf    @ 83886080   16.78 MB  (dead after transpose_v) -> maskT aliases after
  //   Vt    @ 0          16.78 MB
  //   maskT @ 83886080   16.78 MB
  //   AO    @ 16777216   16.78 MB  (aliases dead Wq/Wk)
  bf16_t* Af    = (bf16_t*)(ws + 0);
  bf16_t* Wqb   = (bf16_t*)(ws + 16777216);
  bf16_t* Wvb   = (bf16_t*)(ws + 33554432);
  bf16_t* Wob   = (bf16_t*)(ws + 41943040);
  bf16_t* QK    = (bf16_t*)(ws + 50331648);
  bf16_t* Vf    = (bf16_t*)(ws + 83886080);
  bf16_t* Vt    = (bf16_t*)(ws + 0);
  bf16_t* maskT = (bf16_t*)(ws + 83886080);
  bf16_t* AO    = (bf16_t*)(ws + 16777216);

  cast_hidden<<<8192, 256, 0, stream>>>(hidden, Af);
  cast_weights<<<dim3(4096, 4), 256, 0, stream>>>(Wq, Wk, Wv, Wo, Wqb);

  // QK projection: A(4096x2048) * [Wq;Wk]^T (4096x2048) -> QK  (grid 256, no tail)
  gemm256<<<256, 512, 0, stream>>>(Af, Wqb, QK, nullptr, 4096, LDK, HID);
  // V projection: 128^2 tiles, 512 blocks fully resident
  gemm_bt<<<512, 256, 0, stream>>>(Af, Wvb, Vf, nullptr, 4096, HID, HID);

  rope_qk<<<2048, 256, 0, stream>>>(QK, cost, sint);
  transpose_v<<<dim3(64, 128), 256, 0, stream>>>(Vf, Vt);
  mask_t<<<dim3(64, 64, 2), 256, 0, stream>>>(mask, maskT);

  flash_fwd<<<256, 512, 0, stream>>>(QK, QK + 2048, Vt, maskT, AO);

  gemm_bt<<<512, 256, 0, stream>>>(AO, Wob, nullptr, out, 4096, HID, HID);
}